// Round 3
// baseline (430.658 us; speedup 1.0000x reference)
//
#include <hip/hip_runtime.h>

// out[b,c,h,w] = x[b,c,h+1,w] - x[b,c,h,w]
// x: (16, 64, 512, 512) fp32, out: (16, 64, 511, 512) fp32
//
// Register-carry vertical walk: each thread owns one float4 column (w4) of one
// (b,c) plane and walks CH_H consecutive output rows, carrying the previously
// loaded row in a register -> each input element fetched exactly once.
// Nontemporal stores keep L2 clean for the input stream.

typedef float f32x4 __attribute__((ext_vector_type(4)));

#define H_IN   512
#define H_OUT  511
#define W4     128                 // 512 floats / 4 per row
#define CHUNKS 8
#define CH_H   64                  // output rows per chunk (last chunk: 63)

__global__ __launch_bounds__(256) void PartialDerivative_kernel(
    const f32x4* __restrict__ x, f32x4* __restrict__ out) {
    // t = ((bc * CHUNKS + ck) * W4 + w4)
    const int t  = blockIdx.x * 256 + threadIdx.x;
    const int w4 = t & (W4 - 1);
    const int ck = (t >> 7) & (CHUNKS - 1);
    const int bc = t >> 10;        // 7 (w4 bits) + 3 (chunk bits)

    const int h0   = ck * CH_H;
    const int nout = (ck == CHUNKS - 1) ? (CH_H - 1) : CH_H;

    const f32x4* xp = x   + (size_t)bc * (H_IN * W4)  + (size_t)h0 * W4 + w4;
    f32x4*       op = out + (size_t)bc * (H_OUT * W4) + (size_t)h0 * W4 + w4;

    f32x4 prev = xp[0];
    #pragma unroll 4
    for (int i = 0; i < nout; ++i) {
        f32x4 nxt = xp[(size_t)(i + 1) * W4];
        f32x4 r = nxt - prev;
        __builtin_nontemporal_store(r, &op[(size_t)i * W4]);
        prev = nxt;
    }
}

extern "C" void kernel_launch(void* const* d_in, const int* in_sizes, int n_in,
                              void* d_out, int out_size, void* d_ws, size_t ws_size,
                              hipStream_t stream) {
    const f32x4* x = (const f32x4*)d_in[0];
    f32x4* out = (f32x4*)d_out;

    // total threads = 1024 planes * 8 chunks * 128 w4 = 1,048,576 -> 4096 blocks
    dim3 block(256);
    dim3 grid((16 * 64 * CHUNKS * W4) / 256);
    PartialDerivative_kernel<<<grid, block, 0, stream>>>(x, out);
}